// Round 1
// baseline (1363.201 us; speedup 1.0000x reference)
//
#include <hip/hip_runtime.h>
#include <hip/hip_bf16.h>

typedef __hip_bfloat16 bf16;
typedef __hip_bfloat162 bf16x2;

// ---------------------------------------------------------------- CSR build
__global__ __launch_bounds__(256) void zero_kernel(int* __restrict__ a, int n) {
    int i = blockIdx.x * 256 + threadIdx.x;
    if (i < n) a[i] = 0;
}

__global__ __launch_bounds__(256) void count_kernel(const int* __restrict__ ei,
                                                    int* __restrict__ cnt, int E, int N) {
    int e = blockIdx.x * 256 + threadIdx.x;
    if (e >= E + N) return;
    int d = (e < E) ? ei[(size_t)E + e] : (e - E);   // self-loop for e>=E
    atomicAdd(&cnt[d], 1);
}

// single-block exclusive scan of cnt[0..N) -> rowptr[0..N]
__global__ __launch_bounds__(1024) void scan_kernel(const int* __restrict__ cnt,
                                                    int* __restrict__ rowptr, int N) {
    __shared__ int ps[1024];
    const int tid = threadIdx.x;
    const int chunk = (N + 1023) / 1024;
    const int base = tid * chunk;
    int s = 0;
    for (int i = 0; i < chunk; ++i) { int j = base + i; if (j < N) s += cnt[j]; }
    ps[tid] = s;
    __syncthreads();
    for (int off = 1; off < 1024; off <<= 1) {
        int v = (tid >= off) ? ps[tid - off] : 0;
        __syncthreads();
        ps[tid] += v;
        __syncthreads();
    }
    int run = (tid == 0) ? 0 : ps[tid - 1];
    for (int i = 0; i < chunk; ++i) {
        int j = base + i;
        if (j < N) { rowptr[j] = run; run += cnt[j]; }
    }
    if (tid == 1023) rowptr[N] = run;
}

__global__ __launch_bounds__(256) void scatter_kernel(const int* __restrict__ ei,
                                                      const int* __restrict__ rowptr,
                                                      int* __restrict__ cursor,
                                                      int* __restrict__ csr_src,
                                                      int E, int N) {
    int e = blockIdx.x * 256 + threadIdx.x;
    if (e >= E + N) return;
    int s, d;
    if (e < E) { s = ei[e]; d = ei[(size_t)E + e]; }
    else       { s = e - E; d = e - E; }
    int pos = atomicAdd(&cursor[d], 1);
    csr_src[rowptr[d] + pos] = s;
}

// ---------------------------------------------------------------- GEMM (fp32)
// C[M,Ncols] = act(A[M,128] @ B[128,Ncols] + bias), out fp32 OR bf16.
// BM=BN=128, BK=32, 256 threads, 8x8 per-thread micro-tile.
__global__ __launch_bounds__(256) void gemm_kernel(const float* __restrict__ A,
                                                   const float* __restrict__ B,
                                                   const float* __restrict__ bias,
                                                   float* __restrict__ outF,
                                                   bf16* __restrict__ outB,
                                                   int M, int Ncols, int relu) {
    __shared__ float As[32][132];   // [k][m], +4 pad keeps float4 reads 16B-aligned
    __shared__ float Bs[32][132];   // [k][n]
    const int m0 = blockIdx.x * 128;
    const int n0 = blockIdx.y * 128;
    const int tid = threadIdx.x;
    const int tm = (tid >> 4) * 8;
    const int tn = (tid & 15) * 8;

    float acc[8][8];
#pragma unroll
    for (int i = 0; i < 8; ++i)
#pragma unroll
        for (int j = 0; j < 8; ++j) acc[i][j] = 0.f;

    for (int kk = 0; kk < 128; kk += 32) {
#pragma unroll
        for (int i = 0; i < 16; ++i) {          // A tile: 128 rows x 32 k
            int idx = i * 256 + tid;
            int r = idx >> 5, c = idx & 31;
            int gm = m0 + r;
            As[c][r] = (gm < M) ? A[(size_t)gm * 128 + kk + c] : 0.f;
        }
#pragma unroll
        for (int i = 0; i < 16; ++i) {          // B tile: 32 k x 128 cols
            int idx = i * 256 + tid;
            int r = idx >> 7, c = idx & 127;
            Bs[r][c] = B[(size_t)(kk + r) * Ncols + n0 + c];
        }
        __syncthreads();
#pragma unroll
        for (int k = 0; k < 32; ++k) {
            float a[8], b[8];
            *(float4*)&a[0] = *(const float4*)&As[k][tm];
            *(float4*)&a[4] = *(const float4*)&As[k][tm + 4];
            *(float4*)&b[0] = *(const float4*)&Bs[k][tn];
            *(float4*)&b[4] = *(const float4*)&Bs[k][tn + 4];
#pragma unroll
            for (int i = 0; i < 8; ++i)
#pragma unroll
                for (int j = 0; j < 8; ++j) acc[i][j] = fmaf(a[i], b[j], acc[i][j]);
        }
        __syncthreads();
    }

#pragma unroll
    for (int i = 0; i < 8; ++i) {
        size_t gm = m0 + tm + i;            // out buffers are padded to grid size
#pragma unroll
        for (int j = 0; j < 8; ++j) {
            int gn = n0 + tn + j;
            float v = acc[i][j] + bias[gn];
            if (relu) v = fmaxf(v, 0.f);
            if (outF) outF[gm * Ncols + gn] = v;
            else      outB[gm * Ncols + gn] = __float2bfloat16(v);
        }
    }
}

// ---------------------------------------------------------------- fused GATv2 layer
// block = dst node, wave = head (H=4, C=128; lane handles channels 2l,2l+1).
// Online-softmax over incoming edges (CSR), then head-mean + bias + residual
// + LayerNorm + ReLU; mode 0: write h_out[N,128]; mode 1: write dot(y, head_W)+head_b.
__global__ __launch_bounds__(256) void gat_kernel(const bf16* __restrict__ xl,
                                                  const bf16* __restrict__ xr,
                                                  const float* __restrict__ att,     // [4*128]
                                                  const int* __restrict__ rowptr,
                                                  const int* __restrict__ csr_src,
                                                  const float* __restrict__ h_res,   // [N,128]
                                                  const float* __restrict__ gbias,   // [128]
                                                  const float* __restrict__ ln_g,
                                                  const float* __restrict__ ln_b,
                                                  float* __restrict__ h_out,
                                                  const float* __restrict__ head_W,  // [128]
                                                  const float* __restrict__ head_b,  // [1]
                                                  float* __restrict__ out_scalar,
                                                  int mode) {
    const int n = blockIdx.x;
    const int tid = threadIdx.x;
    const int h = tid >> 6;
    const int lane = tid & 63;
    const int c0 = lane << 1;

    const float att0 = att[h * 128 + c0];
    const float att1 = att[h * 128 + c0 + 1];
    float xr0, xr1;
    {
        bf16x2 v = *(const bf16x2*)(xr + ((size_t)n * 512 + h * 128 + c0));
        xr0 = __low2float(v); xr1 = __high2float(v);
    }
    const int rs = rowptr[n], re = rowptr[n + 1];
    const bf16* xlh = xl + h * 128 + c0;

    float m = -1e30f, l = 0.f, acc0 = 0.f, acc1 = 0.f;
    float nx0 = 0.f, nx1 = 0.f;
    if (re > rs) {                              // prefetch edge rs
        int s = csr_src[rs];
        bf16x2 v = *(const bf16x2*)(xlh + (size_t)s * 512);
        nx0 = __low2float(v); nx1 = __high2float(v);
    }
    for (int e = rs; e < re; ++e) {
        float x0 = nx0, x1 = nx1;
        if (e + 1 < re) {                       // prefetch next edge during reduce
            int s = csr_src[e + 1];
            bf16x2 v = *(const bf16x2*)(xlh + (size_t)s * 512);
            nx0 = __low2float(v); nx1 = __high2float(v);
        }
        float t0 = x0 + xr0; t0 = (t0 > 0.f) ? t0 : 0.2f * t0;   // leaky_relu
        float t1 = x1 + xr1; t1 = (t1 > 0.f) ? t1 : 0.2f * t1;
        float p = fmaf(att0, t0, att1 * t1);
#pragma unroll
        for (int off = 32; off > 0; off >>= 1) p += __shfl_xor(p, off, 64);
        float mn = fmaxf(m, p);
        float sc = __expf(m - mn);              // m=-1e30 first iter -> 0
        float w  = __expf(p - mn);
        l    = fmaf(l,    sc, w);
        acc0 = fmaf(acc0, sc, w * x0);
        acc1 = fmaf(acc1, sc, w * x1);
        m = mn;
    }
    const float inv = 0.25f / (l + 1e-16f);     // alpha-normalize + head-mean

    __shared__ float sm[4][128];
    __shared__ float red[8];
    sm[h][c0]     = acc0 * inv;
    sm[h][c0 + 1] = acc1 * inv;
    __syncthreads();

    float v = 0.f;
    if (tid < 128)
        v = sm[0][tid] + sm[1][tid] + sm[2][tid] + sm[3][tid]
          + gbias[tid] + h_res[(size_t)n * 128 + tid];
    float s1 = v, s2 = v * v;                   // threads >=128 contribute 0
#pragma unroll
    for (int off = 32; off > 0; off >>= 1) {
        s1 += __shfl_xor(s1, off, 64);
        s2 += __shfl_xor(s2, off, 64);
    }
    if (lane == 0) { red[h] = s1; red[4 + h] = s2; }
    __syncthreads();
    const float mu   = (red[0] + red[1] + red[2] + red[3]) * 0.0078125f;
    const float var  = (red[4] + red[5] + red[6] + red[7]) * 0.0078125f - mu * mu;
    const float rstd = rsqrtf(var + 1e-5f);
    float y = 0.f;
    if (tid < 128) {
        y = fmaf((v - mu) * rstd, ln_g[tid], ln_b[tid]);
        y = fmaxf(y, 0.f);                      // relu
    }
    if (mode == 0) {
        if (tid < 128) h_out[(size_t)n * 128 + tid] = y;
    } else {
        float d = (tid < 128) ? y * head_W[tid] : 0.f;
#pragma unroll
        for (int off = 32; off > 0; off >>= 1) d += __shfl_xor(d, off, 64);
        __syncthreads();                        // red about to be rewritten
        if (lane == 0) red[h] = d;
        __syncthreads();
        if (tid == 0) out_scalar[n] = red[0] + red[1] + red[2] + red[3] + head_b[0];
    }
}

// ---------------------------------------------------------------- launch
extern "C" void kernel_launch(void* const* d_in, const int* in_sizes, int n_in,
                              void* d_out, int out_size, void* d_ws, size_t ws_size,
                              hipStream_t stream) {
    const float* x      = (const float*)d_in[0];
    const int*   ei     = (const int*)  d_in[1];
    const float* W_in   = (const float*)d_in[2];
    const float* b_in   = (const float*)d_in[3];
    const float* c1_Wl  = (const float*)d_in[4];
    const float* c1_bl  = (const float*)d_in[5];
    const float* c1_Wr  = (const float*)d_in[6];
    const float* c1_br  = (const float*)d_in[7];
    const float* c1_att = (const float*)d_in[8];
    const float* c1_b   = (const float*)d_in[9];
    const float* ln1_g  = (const float*)d_in[10];
    const float* ln1_b  = (const float*)d_in[11];
    const float* a_Wl   = (const float*)d_in[12];
    const float* a_bl   = (const float*)d_in[13];
    const float* a_Wr   = (const float*)d_in[14];
    const float* a_br   = (const float*)d_in[15];
    const float* a_att  = (const float*)d_in[16];
    const float* a_b    = (const float*)d_in[17];
    const float* aln_g  = (const float*)d_in[18];
    const float* aln_b  = (const float*)d_in[19];
    const float* ah_W   = (const float*)d_in[20];
    const float* ah_b   = (const float*)d_in[21];
    const float* k_Wl   = (const float*)d_in[22];
    const float* k_bl   = (const float*)d_in[23];
    const float* k_Wr   = (const float*)d_in[24];
    const float* k_br   = (const float*)d_in[25];
    const float* k_att  = (const float*)d_in[26];
    const float* k_b    = (const float*)d_in[27];
    const float* kln_g  = (const float*)d_in[28];
    const float* kln_b  = (const float*)d_in[29];
    const float* kh_W   = (const float*)d_in[30];
    const float* kh_b   = (const float*)d_in[31];

    const int N  = in_sizes[0] / 128;       // 20000
    const int E  = in_sizes[1] / 2;         // 320000
    const int ET = E + N;                   // incl. self-loops
    const int MB = (N + 127) / 128;         // 157
    const int Npad = MB * 128;              // 20096 (GEMM writes pad rows harmlessly)

    char* ws = (char*)d_ws;
    size_t off = 0;
    auto alloc = [&](size_t bytes) -> void* {
        void* p = ws + off;
        off += (bytes + 255) & ~(size_t)255;
        return p;
    };
    int*   rowptr  = (int*)alloc((size_t)(N + 1) * 4);
    int*   cnt     = (int*)alloc((size_t)N * 4);
    int*   cursor  = (int*)alloc((size_t)N * 4);
    int*   csr_src = (int*)alloc((size_t)ET * 4);
    float* h0      = (float*)alloc((size_t)Npad * 128 * 4);
    float* h1      = (float*)alloc((size_t)Npad * 128 * 4);
    bf16*  xl1     = (bf16*)alloc((size_t)Npad * 512 * 2);
    bf16*  xr1     = (bf16*)alloc((size_t)Npad * 512 * 2);
    bf16*  xlk     = (bf16*)alloc((size_t)Npad * 512 * 2);
    bf16*  xrk     = (bf16*)alloc((size_t)Npad * 512 * 2);
    bf16*  xla = xl1;  bf16* xra = xr1;     // reuse layer-1 buffers for layer a

    float* out_logits = (float*)d_out;
    float* out_value  = (float*)d_out + N;

    // CSR build (graph is identical for all 3 GAT layers)
    zero_kernel<<<(N + 255) / 256, 256, 0, stream>>>(cnt, N);
    zero_kernel<<<(N + 255) / 256, 256, 0, stream>>>(cursor, N);
    count_kernel<<<(ET + 255) / 256, 256, 0, stream>>>(ei, cnt, E, N);
    scan_kernel<<<1, 1024, 0, stream>>>(cnt, rowptr, N);
    scatter_kernel<<<(ET + 255) / 256, 256, 0, stream>>>(ei, rowptr, cursor, csr_src, E, N);

    // h0 = relu(x @ W_in + b_in)
    gemm_kernel<<<dim3(MB, 1), 256, 0, stream>>>(x, W_in, b_in, h0, nullptr, N, 128, 1);
    // layer-1 transforms (bf16 out for the gather)
    gemm_kernel<<<dim3(MB, 4), 256, 0, stream>>>(h0, c1_Wl, c1_bl, nullptr, xl1, N, 512, 0);
    gemm_kernel<<<dim3(MB, 4), 256, 0, stream>>>(h0, c1_Wr, c1_br, nullptr, xr1, N, 512, 0);
    // h1 = relu(LN(h0 + gat1(h0)))
    gat_kernel<<<N, 256, 0, stream>>>(xl1, xr1, c1_att, rowptr, csr_src, h0, c1_b,
                                      ln1_g, ln1_b, h1, nullptr, nullptr, nullptr, 0);
    // actor / critic transforms
    gemm_kernel<<<dim3(MB, 4), 256, 0, stream>>>(h1, a_Wl, a_bl, nullptr, xla, N, 512, 0);
    gemm_kernel<<<dim3(MB, 4), 256, 0, stream>>>(h1, a_Wr, a_br, nullptr, xra, N, 512, 0);
    gemm_kernel<<<dim3(MB, 4), 256, 0, stream>>>(h1, k_Wl, k_bl, nullptr, xlk, N, 512, 0);
    gemm_kernel<<<dim3(MB, 4), 256, 0, stream>>>(h1, k_Wr, k_br, nullptr, xrk, N, 512, 0);
    // logits / value heads (fully fused epilogues)
    gat_kernel<<<N, 256, 0, stream>>>(xla, xra, a_att, rowptr, csr_src, h1, a_b,
                                      aln_g, aln_b, nullptr, ah_W, ah_b, out_logits, 1);
    gat_kernel<<<N, 256, 0, stream>>>(xlk, xrk, k_att, rowptr, csr_src, h1, k_b,
                                      kln_g, kln_b, nullptr, kh_W, kh_b, out_value, 1);
}

// Round 2
// 509.513 us; speedup vs baseline: 2.6755x; 2.6755x over previous
//
#include <hip/hip_runtime.h>
#include <hip/hip_bf16.h>

typedef __hip_bfloat16 bf16;
typedef __attribute__((ext_vector_type(8))) short short8;
typedef __attribute__((ext_vector_type(4))) short short4_t;
typedef __attribute__((ext_vector_type(4))) float float4_t;

__device__ __forceinline__ float bs2f(short s) {
    return __uint_as_float(((unsigned)(unsigned short)s) << 16);
}
__device__ __forceinline__ short f2bs(float f) {
    bf16 b = __float2bfloat16(f);
    return *(short*)&b;
}

// ---------------------------------------------------------------- CSR build
__global__ __launch_bounds__(256) void zero_kernel(int* __restrict__ a, int n) {
    int i = blockIdx.x * 256 + threadIdx.x;
    if (i < n) a[i] = 0;
}

__global__ __launch_bounds__(256) void count_kernel(const int* __restrict__ ei,
                                                    int* __restrict__ cnt, int E, int N) {
    int e = blockIdx.x * 256 + threadIdx.x;
    if (e >= E + N) return;
    int d = (e < E) ? ei[(size_t)E + e] : (e - E);   // self-loop for e>=E
    atomicAdd(&cnt[d], 1);
}

__global__ __launch_bounds__(1024) void scan_kernel(const int* __restrict__ cnt,
                                                    int* __restrict__ rowptr, int N) {
    __shared__ int ps[1024];
    const int tid = threadIdx.x;
    const int chunk = (N + 1023) / 1024;
    const int base = tid * chunk;
    int s = 0;
    for (int i = 0; i < chunk; ++i) { int j = base + i; if (j < N) s += cnt[j]; }
    ps[tid] = s;
    __syncthreads();
    for (int off = 1; off < 1024; off <<= 1) {
        int v = (tid >= off) ? ps[tid - off] : 0;
        __syncthreads();
        ps[tid] += v;
        __syncthreads();
    }
    int run = (tid == 0) ? 0 : ps[tid - 1];
    for (int i = 0; i < chunk; ++i) {
        int j = base + i;
        if (j < N) { rowptr[j] = run; run += cnt[j]; }
    }
    if (tid == 1023) rowptr[N] = run;
}

__global__ __launch_bounds__(256) void scatter_kernel(const int* __restrict__ ei,
                                                      const int* __restrict__ rowptr,
                                                      int* __restrict__ cursor,
                                                      int* __restrict__ csr_src,
                                                      int E, int N) {
    int e = blockIdx.x * 256 + threadIdx.x;
    if (e >= E + N) return;
    int s, d;
    if (e < E) { s = ei[e]; d = ei[(size_t)E + e]; }
    else       { s = e - E; d = e - E; }
    int pos = atomicAdd(&cursor[d], 1);
    csr_src[rowptr[d] + pos] = s;
}

// ---------------------------------------------------------------- weight prep
// Wt (bf16, [n][k] transposed): seg0 W_in [128], seg1 c1 Wl|Wr [1024], seg2 a/k [2048]
__global__ __launch_bounds__(256) void convert_w_kernel(
        const float* __restrict__ W_in,
        const float* __restrict__ c1_Wl, const float* __restrict__ c1_Wr,
        const float* __restrict__ a_Wl, const float* __restrict__ a_Wr,
        const float* __restrict__ k_Wl, const float* __restrict__ k_Wr,
        bf16* __restrict__ Wt) {
    int idx = blockIdx.x * 256 + threadIdx.x;
    if (idx >= 3200 * 128) return;
    int row = idx >> 7, k = idx & 127;
    float v;
    if (row < 128) {
        v = W_in[k * 128 + row];
    } else if (row < 1152) {
        int n = row - 128;
        v = (n < 512) ? c1_Wl[k * 512 + n] : c1_Wr[k * 512 + (n - 512)];
    } else {
        int n = row - 1152;
        const float* W = (n < 512) ? a_Wl : (n < 1024) ? a_Wr : (n < 1536) ? k_Wl : k_Wr;
        v = W[k * 512 + (n & 511)];
    }
    Wt[idx] = __float2bfloat16(v);
}

__global__ __launch_bounds__(256) void bias_kernel(
        const float* __restrict__ c1_bl, const float* __restrict__ c1_br,
        const float* __restrict__ a_bl, const float* __restrict__ a_br,
        const float* __restrict__ k_bl, const float* __restrict__ k_br,
        float* __restrict__ b1, float* __restrict__ bak) {
    int i = blockIdx.x * 256 + threadIdx.x;
    if (i < 1024) {
        b1[i] = (i < 512) ? c1_bl[i] : c1_br[i - 512];
    } else if (i < 3072) {
        int j = i - 1024;
        const float* b = (j < 512) ? a_bl : (j < 1024) ? a_br : (j < 1536) ? k_bl : k_br;
        bak[j] = b[j & 511];
    }
}

// ---------------------------------------------------------------- MFMA GEMM
// C[M,Nc] = act(A[M,128] @ W + bias); A fp32 (cast to bf16 in staging),
// W pre-transposed bf16 [Nc][128]. 128x128 tile, K=128 single pass.
__global__ __launch_bounds__(256, 2) void gemm_mfma_kernel(
        const float* __restrict__ A, const bf16* __restrict__ Wt,
        const float* __restrict__ bias,
        float* __restrict__ outF, bf16* __restrict__ outB,
        int M, int Nc, int relu) {
    __shared__ short As[128][136];   // [m][k], +8 pad: rows land on distinct bank groups
    __shared__ short Bs[128][136];   // [n][k]
    const int tid = threadIdx.x;
    const int m0 = blockIdx.x * 128;
    const int n0 = blockIdx.y * 128;

#pragma unroll
    for (int i = 0; i < 16; ++i) {            // stage A: 4096 float4 loads
        int idx = i * 256 + tid;
        int r = idx >> 5, k4 = (idx & 31) * 4;
        int gm = m0 + r;
        float4 v = (gm < M) ? *(const float4*)&A[(size_t)gm * 128 + k4]
                            : make_float4(0.f, 0.f, 0.f, 0.f);
        short4_t s;
        s.x = f2bs(v.x); s.y = f2bs(v.y); s.z = f2bs(v.z); s.w = f2bs(v.w);
        *(short4_t*)&As[r][k4] = s;
    }
#pragma unroll
    for (int i = 0; i < 8; ++i) {             // stage B: 2048 16B copies
        int idx = i * 256 + tid;
        int nr = idx >> 4, k8 = (idx & 15) * 8;
        *(short8*)&Bs[nr][k8] = *(const short8*)&Wt[(size_t)(n0 + nr) * 128 + k8];
    }
    __syncthreads();

    const int lane = tid & 63;
    const int w = tid >> 6;
    const int wm = (w >> 1) * 64, wn = (w & 1) * 64;
    const int fr = lane & 15;                 // fragment row (A) / col (B)
    const int fq = (lane >> 4) * 8;           // fragment k offset

    float4_t acc[4][4] = {};
#pragma unroll
    for (int kk = 0; kk < 128; kk += 32) {
        short8 a[4], b[4];
#pragma unroll
        for (int t = 0; t < 4; ++t) a[t] = *(const short8*)&As[wm + t * 16 + fr][kk + fq];
#pragma unroll
        for (int t = 0; t < 4; ++t) b[t] = *(const short8*)&Bs[wn + t * 16 + fr][kk + fq];
#pragma unroll
        for (int ti = 0; ti < 4; ++ti)
#pragma unroll
            for (int tj = 0; tj < 4; ++tj)
                acc[ti][tj] = __builtin_amdgcn_mfma_f32_16x16x32_bf16(
                    a[ti], b[tj], acc[ti][tj], 0, 0, 0);
    }

    const int r0 = (lane >> 4) * 4;           // C/D: col=lane&15, row=quad*4+reg
#pragma unroll
    for (int ti = 0; ti < 4; ++ti) {
#pragma unroll
        for (int tj = 0; tj < 4; ++tj) {
            int col = n0 + wn + tj * 16 + fr;
            float bz = bias[col];
#pragma unroll
            for (int r = 0; r < 4; ++r) {
                size_t row = m0 + wm + ti * 16 + r0 + r;
                float v = acc[ti][tj][r] + bz;
                if (relu) v = fmaxf(v, 0.f);
                if (outF) outF[row * Nc + col] = v;
                else      outB[row * Nc + col] = __float2bfloat16(v);
            }
        }
    }
}

// ---------------------------------------------------------------- fused GATv2 layer
// block = dst node, wave = head. Within a wave: 4 edge-groups x 16 lanes,
// each lane owns 8 channels (16B loads). 4 independent online-softmax streams,
// merged at the end; then head-mean + bias + residual + LN + ReLU (+head dot).
__global__ __launch_bounds__(256) void gat_kernel(
        const bf16* __restrict__ xl, const bf16* __restrict__ xr, int stride,
        const float* __restrict__ att,      // [4*128]
        const int* __restrict__ rowptr, const int* __restrict__ csr_src,
        const float* __restrict__ h_res,    // [N,128]
        const float* __restrict__ gbias,    // [128]
        const float* __restrict__ ln_g, const float* __restrict__ ln_b,
        float* __restrict__ h_out,
        const float* __restrict__ head_W, const float* __restrict__ head_b,
        float* __restrict__ out_scalar, int mode) {
    const int n = blockIdx.x;
    const int tid = threadIdx.x;
    const int h = tid >> 6;
    const int lane = tid & 63;
    const int g = lane >> 4;
    const int sl = lane & 15;
    const int cb = sl * 8;

    float att8[8], xr8[8];
    {
        const float* ap = att + h * 128 + cb;
#pragma unroll
        for (int j = 0; j < 8; ++j) att8[j] = ap[j];
        short8 v = *(const short8*)(xr + (size_t)n * stride + h * 128 + cb);
#pragma unroll
        for (int j = 0; j < 8; ++j) xr8[j] = bs2f(v[j]);
    }
    const int rs = rowptr[n], re = rowptr[n + 1];
    const int nit = (re - rs + 3) >> 2;
    const bf16* xlh = xl + h * 128 + cb;

    float m = -1e30f, l = 0.f;
    float acc[8] = {};
    int e = rs + g;
    int s0 = (e < re) ? csr_src[e] : n;
    short8 v_next = *(const short8*)(xlh + (size_t)s0 * stride);

    for (int it = 0; it < nit; ++it, e += 4) {
        const bool valid = (e < re);
        short8 vc = v_next;
        if (e + 4 < re) {                      // prefetch next group-edge
            int s2 = csr_src[e + 4];
            v_next = *(const short8*)(xlh + (size_t)s2 * stride);
        }
        float x[8];
#pragma unroll
        for (int j = 0; j < 8; ++j) x[j] = bs2f(vc[j]);
        float p = 0.f;
#pragma unroll
        for (int j = 0; j < 8; ++j) {
            float t = x[j] + xr8[j];
            t = fmaxf(t, 0.f) + 0.2f * fminf(t, 0.f);    // leaky_relu
            p = fmaf(att8[j], t, p);
        }
        p += __shfl_xor(p, 1, 64);             // reduce over the 16-lane group
        p += __shfl_xor(p, 2, 64);
        p += __shfl_xor(p, 4, 64);
        p += __shfl_xor(p, 8, 64);
        if (!valid) p = -1e30f;
        float mn = fmaxf(m, p);
        float sc = __expf(m - mn);
        float wv = valid ? __expf(p - mn) : 0.f;
        l = fmaf(l, sc, wv);
#pragma unroll
        for (int j = 0; j < 8; ++j) acc[j] = fmaf(acc[j], sc, wv * x[j]);
        m = mn;
    }
    // merge the 4 group streams (offsets 16, 32)
#pragma unroll
    for (int off = 16; off <= 32; off <<= 1) {
        float m2 = __shfl_xor(m, off, 64);
        float l2 = __shfl_xor(l, off, 64);
        float mn = fmaxf(m, m2);
        float sa = __expf(m - mn);
        float sb = __expf(m2 - mn);
        l = l * sa + l2 * sb;
#pragma unroll
        for (int j = 0; j < 8; ++j) {
            float a2 = __shfl_xor(acc[j], off, 64);
            acc[j] = acc[j] * sa + a2 * sb;
        }
        m = mn;
    }
    const float inv = 0.25f / (l + 1e-16f);    // alpha-normalize + head-mean

    __shared__ float sm[4][128];
    __shared__ float red[8];
    if (g == 0) {
#pragma unroll
        for (int j = 0; j < 8; ++j) sm[h][cb + j] = acc[j] * inv;
    }
    __syncthreads();

    float v = 0.f;
    if (tid < 128)
        v = sm[0][tid] + sm[1][tid] + sm[2][tid] + sm[3][tid]
          + gbias[tid] + h_res[(size_t)n * 128 + tid];
    float s1 = v, s2 = v * v;
#pragma unroll
    for (int off = 32; off > 0; off >>= 1) {
        s1 += __shfl_xor(s1, off, 64);
        s2 += __shfl_xor(s2, off, 64);
    }
    if (lane == 0) { red[h] = s1; red[4 + h] = s2; }
    __syncthreads();
    const float mu   = (red[0] + red[1] + red[2] + red[3]) * 0.0078125f;
    const float var  = (red[4] + red[5] + red[6] + red[7]) * 0.0078125f - mu * mu;
    const float rstd = rsqrtf(var + 1e-5f);
    float y = 0.f;
    if (tid < 128) {
        y = fmaf((v - mu) * rstd, ln_g[tid], ln_b[tid]);
        y = fmaxf(y, 0.f);
    }
    if (mode == 0) {
        if (tid < 128) h_out[(size_t)n * 128 + tid] = y;
    } else {
        float d = (tid < 128) ? y * head_W[tid] : 0.f;
#pragma unroll
        for (int off = 32; off > 0; off >>= 1) d += __shfl_xor(d, off, 64);
        __syncthreads();
        if (lane == 0) red[h] = d;
        __syncthreads();
        if (tid == 0) out_scalar[n] = red[0] + red[1] + red[2] + red[3] + head_b[0];
    }
}

// ---------------------------------------------------------------- launch
extern "C" void kernel_launch(void* const* d_in, const int* in_sizes, int n_in,
                              void* d_out, int out_size, void* d_ws, size_t ws_size,
                              hipStream_t stream) {
    const float* x      = (const float*)d_in[0];
    const int*   ei     = (const int*)  d_in[1];
    const float* W_in   = (const float*)d_in[2];
    const float* b_in   = (const float*)d_in[3];
    const float* c1_Wl  = (const float*)d_in[4];
    const float* c1_bl  = (const float*)d_in[5];
    const float* c1_Wr  = (const float*)d_in[6];
    const float* c1_br  = (const float*)d_in[7];
    const float* c1_att = (const float*)d_in[8];
    const float* c1_b   = (const float*)d_in[9];
    const float* ln1_g  = (const float*)d_in[10];
    const float* ln1_b  = (const float*)d_in[11];
    const float* a_Wl   = (const float*)d_in[12];
    const float* a_bl   = (const float*)d_in[13];
    const float* a_Wr   = (const float*)d_in[14];
    const float* a_br   = (const float*)d_in[15];
    const float* a_att  = (const float*)d_in[16];
    const float* a_b    = (const float*)d_in[17];
    const float* aln_g  = (const float*)d_in[18];
    const float* aln_b  = (const float*)d_in[19];
    const float* ah_W   = (const float*)d_in[20];
    const float* ah_b   = (const float*)d_in[21];
    const float* k_Wl   = (const float*)d_in[22];
    const float* k_bl   = (const float*)d_in[23];
    const float* k_Wr   = (const float*)d_in[24];
    const float* k_br   = (const float*)d_in[25];
    const float* k_att  = (const float*)d_in[26];
    const float* k_b    = (const float*)d_in[27];
    const float* kln_g  = (const float*)d_in[28];
    const float* kln_b  = (const float*)d_in[29];
    const float* kh_W   = (const float*)d_in[30];
    const float* kh_b   = (const float*)d_in[31];

    const int N  = in_sizes[0] / 128;       // 20000
    const int E  = in_sizes[1] / 2;         // 320000
    const int ET = E + N;
    const int MB = (N + 127) / 128;         // 157
    const int Npad = MB * 128;              // 20096

    char* ws = (char*)d_ws;
    size_t off = 0;
    auto alloc = [&](size_t bytes) -> void* {
        void* p = ws + off;
        off += (bytes + 255) & ~(size_t)255;
        return p;
    };
    int*   rowptr  = (int*)alloc((size_t)(N + 1) * 4);
    int*   cnt     = (int*)alloc((size_t)N * 4);
    int*   cursor  = (int*)alloc((size_t)N * 4);
    int*   csr_src = (int*)alloc((size_t)ET * 4);
    float* h0      = (float*)alloc((size_t)Npad * 128 * 4);
    float* h1      = (float*)alloc((size_t)Npad * 128 * 4);
    bf16*  Wt      = (bf16*)alloc((size_t)3200 * 128 * 2);
    float* b1cat   = (float*)alloc(1024 * 4);
    float* bakcat  = (float*)alloc(2048 * 4);
    bf16*  cat     = (bf16*)alloc((size_t)Npad * 2048 * 2);  // layer1 reuses as [.,1024]

    const bf16* Wt_in = Wt;
    const bf16* Wt_1  = Wt + 128 * 128;
    const bf16* Wt_ak = Wt + 128 * 128 + 1024 * 128;

    float* out_logits = (float*)d_out;
    float* out_value  = (float*)d_out + N;

    // CSR (graph shared by all 3 GAT layers) + weight prep
    zero_kernel<<<(N + 255) / 256, 256, 0, stream>>>(cnt, N);
    zero_kernel<<<(N + 255) / 256, 256, 0, stream>>>(cursor, N);
    count_kernel<<<(ET + 255) / 256, 256, 0, stream>>>(ei, cnt, E, N);
    convert_w_kernel<<<1600, 256, 0, stream>>>(W_in, c1_Wl, c1_Wr, a_Wl, a_Wr, k_Wl, k_Wr, Wt);
    bias_kernel<<<12, 256, 0, stream>>>(c1_bl, c1_br, a_bl, a_br, k_bl, k_br, b1cat, bakcat);
    scan_kernel<<<1, 1024, 0, stream>>>(cnt, rowptr, N);
    scatter_kernel<<<(ET + 255) / 256, 256, 0, stream>>>(ei, rowptr, cursor, csr_src, E, N);

    // h0 = relu(x @ W_in + b_in)
    gemm_mfma_kernel<<<dim3(MB, 1), 256, 0, stream>>>(x, Wt_in, b_in, h0, nullptr, N, 128, 1);
    // layer-1: [xl1|xr1] = h0 @ [Wl|Wr]  (bf16 out, row stride 1024)
    gemm_mfma_kernel<<<dim3(MB, 8), 256, 0, stream>>>(h0, Wt_1, b1cat, nullptr, cat, Npad, 1024, 0);
    gat_kernel<<<N, 256, 0, stream>>>(cat, cat + 512, 1024, c1_att, rowptr, csr_src,
                                      h0, c1_b, ln1_g, ln1_b, h1,
                                      nullptr, nullptr, nullptr, 0);
    // actor+critic: [xla|xra|xlk|xrk] = h1 @ [aWl|aWr|kWl|kWr] (row stride 2048)
    gemm_mfma_kernel<<<dim3(MB, 16), 256, 0, stream>>>(h1, Wt_ak, bakcat, nullptr, cat, Npad, 2048, 0);
    gat_kernel<<<N, 256, 0, stream>>>(cat, cat + 512, 2048, a_att, rowptr, csr_src,
                                      h1, a_b, aln_g, aln_b, nullptr,
                                      ah_W, ah_b, out_logits, 1);
    gat_kernel<<<N, 256, 0, stream>>>(cat + 1024, cat + 1536, 2048, k_att, rowptr, csr_src,
                                      h1, k_b, kln_g, kln_b, nullptr,
                                      kh_W, kh_b, out_value, 1);
}

// Round 3
// 500.117 us; speedup vs baseline: 2.7258x; 1.0188x over previous
//
#include <hip/hip_runtime.h>
#include <hip/hip_bf16.h>

typedef __hip_bfloat16 bf16;
typedef __attribute__((ext_vector_type(8))) short short8;
typedef __attribute__((ext_vector_type(4))) short short4_t;
typedef __attribute__((ext_vector_type(4))) float float4_t;
typedef __attribute__((ext_vector_type(2))) float float2v;
typedef __attribute__((ext_vector_type(2))) unsigned int uint2v;

__device__ __forceinline__ short f2bs(float f) {
    bf16 b = __float2bfloat16(f);
    return *(short*)&b;
}

// ---------------------------------------------------------------- CSR build
__global__ __launch_bounds__(256) void zero_kernel(int* __restrict__ a, int n) {
    int i = blockIdx.x * 256 + threadIdx.x;
    if (i < n) a[i] = 0;
}

__global__ __launch_bounds__(256) void count_kernel(const int* __restrict__ ei,
                                                    int* __restrict__ cnt, int E, int N) {
    int e = blockIdx.x * 256 + threadIdx.x;
    if (e >= E + N) return;
    int d = (e < E) ? ei[(size_t)E + e] : (e - E);   // self-loop for e>=E
    atomicAdd(&cnt[d], 1);
}

__global__ __launch_bounds__(1024) void scan_kernel(const int* __restrict__ cnt,
                                                    int* __restrict__ rowptr, int N) {
    __shared__ int ps[1024];
    const int tid = threadIdx.x;
    const int chunk = (N + 1023) / 1024;
    const int base = tid * chunk;
    int s = 0;
    for (int i = 0; i < chunk; ++i) { int j = base + i; if (j < N) s += cnt[j]; }
    ps[tid] = s;
    __syncthreads();
    for (int off = 1; off < 1024; off <<= 1) {
        int v = (tid >= off) ? ps[tid - off] : 0;
        __syncthreads();
        ps[tid] += v;
        __syncthreads();
    }
    int run = (tid == 0) ? 0 : ps[tid - 1];
    for (int i = 0; i < chunk; ++i) {
        int j = base + i;
        if (j < N) { rowptr[j] = run; run += cnt[j]; }
    }
    if (tid == 1023) rowptr[N] = run;
}

// stores BYTE offsets (src * 4096): both gat layers use row stride 2048 bf16
__global__ __launch_bounds__(256) void scatter_kernel(const int* __restrict__ ei,
                                                      const int* __restrict__ rowptr,
                                                      int* __restrict__ cursor,
                                                      int* __restrict__ csr_off,
                                                      int E, int N) {
    int e = blockIdx.x * 256 + threadIdx.x;
    if (e >= E + N) return;
    int s, d;
    if (e < E) { s = ei[e]; d = ei[(size_t)E + e]; }
    else       { s = e - E; d = e - E; }
    int pos = atomicAdd(&cursor[d], 1);
    csr_off[rowptr[d] + pos] = s * 4096;
}

// ---------------------------------------------------------------- weight prep
// LDS-tiled transpose+cast: Wt[n][k] bf16. 7 segments, all k=128.
__global__ __launch_bounds__(256) void transpose_w_kernel(
        const float* __restrict__ W_in,
        const float* __restrict__ c1_Wl, const float* __restrict__ c1_Wr,
        const float* __restrict__ a_Wl, const float* __restrict__ a_Wr,
        const float* __restrict__ k_Wl, const float* __restrict__ k_Wr,
        bf16* __restrict__ Wt) {
    __shared__ float tile[32][33];
    const float* src; int nc, drow;
    switch (blockIdx.z) {
        case 0: src = W_in;  nc = 128; drow = 0;    break;
        case 1: src = c1_Wl; nc = 512; drow = 128;  break;
        case 2: src = c1_Wr; nc = 512; drow = 640;  break;
        case 3: src = a_Wl;  nc = 512; drow = 1152; break;
        case 4: src = a_Wr;  nc = 512; drow = 1664; break;
        case 5: src = k_Wl;  nc = 512; drow = 2176; break;
        default: src = k_Wr; nc = 512; drow = 2688; break;
    }
    const int n0 = blockIdx.x * 32;
    if (n0 >= nc) return;
    const int k0 = blockIdx.y * 32;
    const int tx = threadIdx.x & 31, ty = threadIdx.x >> 5;
#pragma unroll
    for (int i = 0; i < 4; ++i)
        tile[ty + i * 8][tx] = src[(size_t)(k0 + ty + i * 8) * nc + n0 + tx];
    __syncthreads();
#pragma unroll
    for (int i = 0; i < 4; ++i)
        Wt[(size_t)(drow + n0 + ty + i * 8) * 128 + k0 + tx] =
            __float2bfloat16(tile[tx][ty + i * 8]);
}

__global__ __launch_bounds__(256) void bias_kernel(
        const float* __restrict__ c1_bl, const float* __restrict__ c1_br,
        const float* __restrict__ a_bl, const float* __restrict__ a_br,
        const float* __restrict__ k_bl, const float* __restrict__ k_br,
        float* __restrict__ b1, float* __restrict__ bak) {
    int i = blockIdx.x * 256 + threadIdx.x;
    if (i < 1024) {
        b1[i] = (i < 512) ? c1_bl[i] : c1_br[i - 512];
    } else if (i < 3072) {
        int j = i - 1024;
        const float* b = (j < 512) ? a_bl : (j < 1024) ? a_br : (j < 1536) ? k_bl : k_br;
        bak[j] = b[j & 511];
    }
}

// ---------------------------------------------------------------- MFMA GEMM
// C[M,:Nc] (row stride ldc) = act(A[M,128] @ W + bias); A fp32 -> bf16 staging,
// W pre-transposed bf16 [Nc][128]. 128x128 tile, K=128 single pass.
__global__ __launch_bounds__(256, 2) void gemm_mfma_kernel(
        const float* __restrict__ A, const bf16* __restrict__ Wt,
        const float* __restrict__ bias,
        float* __restrict__ outF, bf16* __restrict__ outB,
        int M, int ldc, int relu) {
    __shared__ short As[128][136];   // [m][k]
    __shared__ short Bs[128][136];   // [n][k]
    const int tid = threadIdx.x;
    const int m0 = blockIdx.x * 128;
    const int n0 = blockIdx.y * 128;

#pragma unroll
    for (int i = 0; i < 16; ++i) {            // stage A
        int idx = i * 256 + tid;
        int r = idx >> 5, k4 = (idx & 31) * 4;
        int gm = m0 + r;
        float4 v = (gm < M) ? *(const float4*)&A[(size_t)gm * 128 + k4]
                            : make_float4(0.f, 0.f, 0.f, 0.f);
        short4_t s;
        s.x = f2bs(v.x); s.y = f2bs(v.y); s.z = f2bs(v.z); s.w = f2bs(v.w);
        *(short4_t*)&As[r][k4] = s;
    }
#pragma unroll
    for (int i = 0; i < 8; ++i) {             // stage B
        int idx = i * 256 + tid;
        int nr = idx >> 4, k8 = (idx & 15) * 8;
        *(short8*)&Bs[nr][k8] = *(const short8*)&Wt[(size_t)(n0 + nr) * 128 + k8];
    }
    __syncthreads();

    const int lane = tid & 63;
    const int w = tid >> 6;
    const int wm = (w >> 1) * 64, wn = (w & 1) * 64;
    const int fr = lane & 15;
    const int fq = (lane >> 4) * 8;

    float4_t acc[4][4] = {};
#pragma unroll
    for (int kk = 0; kk < 128; kk += 32) {
        short8 a[4], b[4];
#pragma unroll
        for (int t = 0; t < 4; ++t) a[t] = *(const short8*)&As[wm + t * 16 + fr][kk + fq];
#pragma unroll
        for (int t = 0; t < 4; ++t) b[t] = *(const short8*)&Bs[wn + t * 16 + fr][kk + fq];
#pragma unroll
        for (int ti = 0; ti < 4; ++ti)
#pragma unroll
            for (int tj = 0; tj < 4; ++tj)
                acc[ti][tj] = __builtin_amdgcn_mfma_f32_16x16x32_bf16(
                    a[ti], b[tj], acc[ti][tj], 0, 0, 0);
    }

    const int r0 = (lane >> 4) * 4;           // C/D: col=lane&15, row=quad*4+reg
#pragma unroll
    for (int ti = 0; ti < 4; ++ti) {
#pragma unroll
        for (int tj = 0; tj < 4; ++tj) {
            int col = n0 + wn + tj * 16 + fr;
            float bz = bias[col];
#pragma unroll
            for (int r = 0; r < 4; ++r) {
                size_t row = m0 + wm + ti * 16 + r0 + r;
                float v = acc[ti][tj][r] + bz;
                if (relu) v = fmaxf(v, 0.f);
                if (outF) outF[row * ldc + col] = v;
                else      outB[row * ldc + col] = __float2bfloat16(v);
            }
        }
    }
}

// ---------------------------------------------------------------- fused GATv2 layer
// block = dst node, wave = head. 4 edge-groups x 16 lanes, 8 ch/lane (16B loads).
// No-max softmax (scores are O(+-4); clamp at 60 keeps exp finite; softmax is
// shift-invariant so result matches the reference's segment_max form).
// leaky(t) = 0.6t + 0.4|t| -> 2 packed fmas with pre-scaled att vectors.
__global__ __launch_bounds__(256) void gat_kernel(
        const bf16* __restrict__ xl, const bf16* __restrict__ xr,  // stride 2048
        const float* __restrict__ att,      // [4*128]
        const int* __restrict__ rowptr, const int* __restrict__ csr_off,
        const float* __restrict__ h_res,    // [N,128]
        const float* __restrict__ gbias,    // [128]
        const float* __restrict__ ln_g, const float* __restrict__ ln_b,
        float* __restrict__ h_out,
        const float* __restrict__ head_W, const float* __restrict__ head_b,
        float* __restrict__ out_scalar, int mode) {
    const int n = blockIdx.x;
    const int tid = threadIdx.x;
    const int h = tid >> 6;
    const int lane = tid & 63;
    const int g = lane >> 4;
    const int sl = lane & 15;
    const int cb = sl * 8;

    float2v c1[4], c2[4], xr2[4];
    {
        const float* ap = att + h * 128 + cb;
        short8 v = *(const short8*)(xr + (size_t)n * 2048 + h * 128 + cb);
        const unsigned int* uv = (const unsigned int*)&v;
#pragma unroll
        for (int j = 0; j < 4; ++j) {
            float a0 = ap[2 * j], a1 = ap[2 * j + 1];
            c1[j].x = 0.6f * a0; c1[j].y = 0.6f * a1;
            c2[j].x = 0.4f * a0; c2[j].y = 0.4f * a1;
            unsigned u = uv[j];
            xr2[j].x = __uint_as_float(u << 16);
            xr2[j].y = __uint_as_float(u & 0xffff0000u);
        }
    }
    const int rs = rowptr[n], re = rowptr[n + 1];
    const int nit = (re - rs + 3) >> 2;
    const char* xlh = (const char*)xl + (size_t)(h * 128 + cb) * 2;

    float l = 0.f;
    float2v acc2[4] = {};
    int e = rs + g;
    int off0 = (e < re) ? csr_off[e] : n * 4096;
    short8 v_next = *(const short8*)(xlh + off0);

    for (int it = 0; it < nit; ++it, e += 4) {
        const bool valid = (e < re);
        short8 vc = v_next;
        if (e + 4 < re) {                      // prefetch next group-edge
            int o2 = csr_off[e + 4];
            v_next = *(const short8*)(xlh + o2);
        }
        const unsigned int* uv = (const unsigned int*)&vc;
        float2v p2 = {0.f, 0.f};
        float2v xs[4];
#pragma unroll
        for (int j = 0; j < 4; ++j) {
            unsigned u = uv[j];
            float2v x;
            x.x = __uint_as_float(u << 16);
            x.y = __uint_as_float(u & 0xffff0000u);
            xs[j] = x;
            float2v t = x + xr2[j];
            float2v ta = __builtin_bit_cast(float2v,
                           __builtin_bit_cast(uint2v, t) & 0x7fffffffu);
            p2 = __builtin_elementwise_fma(c1[j], t, p2);
            p2 = __builtin_elementwise_fma(c2[j], ta, p2);
        }
        float p = p2.x + p2.y;
        p += __shfl_xor(p, 1, 64);
        p += __shfl_xor(p, 2, 64);
        p += __shfl_xor(p, 4, 64);
        p += __shfl_xor(p, 8, 64);
        p = valid ? fminf(p, 60.f) : -1e30f;   // exp(-1e30)=0 kills invalid lanes
        float wv = __expf(p);
        l += wv;
        float2v ws = {wv, wv};
#pragma unroll
        for (int j = 0; j < 4; ++j)
            acc2[j] = __builtin_elementwise_fma(ws, xs[j], acc2[j]);
    }
    // merge the 4 group streams: plain sums (no max tracking)
    float* accf = (float*)acc2;
#pragma unroll
    for (int off = 16; off <= 32; off <<= 1) {
        l += __shfl_xor(l, off, 64);
#pragma unroll
        for (int j = 0; j < 8; ++j) accf[j] += __shfl_xor(accf[j], off, 64);
    }
    const float inv = 0.25f / (l + 1e-16f);    // alpha-normalize + head-mean

    __shared__ float sm[4][128];
    __shared__ float red[8];
    if (g == 0) {
#pragma unroll
        for (int j = 0; j < 8; ++j) sm[h][cb + j] = accf[j] * inv;
    }
    __syncthreads();

    float v = 0.f;
    if (tid < 128)
        v = sm[0][tid] + sm[1][tid] + sm[2][tid] + sm[3][tid]
          + gbias[tid] + h_res[(size_t)n * 128 + tid];
    float s1 = v, s2 = v * v;
#pragma unroll
    for (int off = 32; off > 0; off >>= 1) {
        s1 += __shfl_xor(s1, off, 64);
        s2 += __shfl_xor(s2, off, 64);
    }
    if (lane == 0) { red[h] = s1; red[4 + h] = s2; }
    __syncthreads();
    const float mu   = (red[0] + red[1] + red[2] + red[3]) * 0.0078125f;
    const float var  = (red[4] + red[5] + red[6] + red[7]) * 0.0078125f - mu * mu;
    const float rstd = rsqrtf(var + 1e-5f);
    float y = 0.f;
    if (tid < 128) {
        y = fmaf((v - mu) * rstd, ln_g[tid], ln_b[tid]);
        y = fmaxf(y, 0.f);
    }
    if (mode == 0) {
        if (tid < 128) h_out[(size_t)n * 128 + tid] = y;
    } else {
        float d = (tid < 128) ? y * head_W[tid] : 0.f;
#pragma unroll
        for (int off = 32; off > 0; off >>= 1) d += __shfl_xor(d, off, 64);
        __syncthreads();
        if (lane == 0) red[h] = d;
        __syncthreads();
        if (tid == 0) out_scalar[n] = red[0] + red[1] + red[2] + red[3] + head_b[0];
    }
}

// ---------------------------------------------------------------- launch
extern "C" void kernel_launch(void* const* d_in, const int* in_sizes, int n_in,
                              void* d_out, int out_size, void* d_ws, size_t ws_size,
                              hipStream_t stream) {
    const float* x      = (const float*)d_in[0];
    const int*   ei     = (const int*)  d_in[1];
    const float* W_in   = (const float*)d_in[2];
    const float* b_in   = (const float*)d_in[3];
    const float* c1_Wl  = (const float*)d_in[4];
    const float* c1_bl  = (const float*)d_in[5];
    const float* c1_Wr  = (const float*)d_in[6];
    const float* c1_br  = (const float*)d_in[7];
    const float* c1_att = (const float*)d_in[8];
    const float* c1_b   = (const float*)d_in[9];
    const float* ln1_g  = (const float*)d_in[10];
    const float* ln1_b  = (const float*)d_in[11];
    const float* a_Wl   = (const float*)d_in[12];
    const float* a_bl   = (const float*)d_in[13];
    const float* a_Wr   = (const float*)d_in[14];
    const float* a_br   = (const float*)d_in[15];
    const float* a_att  = (const float*)d_in[16];
    const float* a_b    = (const float*)d_in[17];
    const float* aln_g  = (const float*)d_in[18];
    const float* aln_b  = (const float*)d_in[19];
    const float* ah_W   = (const float*)d_in[20];
    const float* ah_b   = (const float*)d_in[21];
    const float* k_Wl   = (const float*)d_in[22];
    const float* k_bl   = (const float*)d_in[23];
    const float* k_Wr   = (const float*)d_in[24];
    const float* k_br   = (const float*)d_in[25];
    const float* k_att  = (const float*)d_in[26];
    const float* k_b    = (const float*)d_in[27];
    const float* kln_g  = (const float*)d_in[28];
    const float* kln_b  = (const float*)d_in[29];
    const float* kh_W   = (const float*)d_in[30];
    const float* kh_b   = (const float*)d_in[31];

    const int N  = in_sizes[0] / 128;       // 20000
    const int E  = in_sizes[1] / 2;         // 320000
    const int ET = E + N;
    const int MB = (N + 127) / 128;         // 157
    const int Npad = MB * 128;              // 20096

    char* ws = (char*)d_ws;
    size_t off = 0;
    auto alloc = [&](size_t bytes) -> void* {
        void* p = ws + off;
        off += (bytes + 255) & ~(size_t)255;
        return p;
    };
    int*   rowptr  = (int*)alloc((size_t)(N + 1) * 4);
    int*   cntcur  = (int*)alloc((size_t)2 * N * 4);   // cnt | cursor
    int*   csr_off = (int*)alloc((size_t)ET * 4);
    float* h0      = (float*)alloc((size_t)Npad * 128 * 4);
    float* h1      = (float*)alloc((size_t)Npad * 128 * 4);
    bf16*  Wt      = (bf16*)alloc((size_t)3200 * 128 * 2);
    float* b1cat   = (float*)alloc(1024 * 4);
    float* bakcat  = (float*)alloc(2048 * 4);
    bf16*  cat     = (bf16*)alloc((size_t)Npad * 2048 * 2);  // row stride 2048 always

    int* cnt    = cntcur;
    int* cursor = cntcur + N;
    const bf16* Wt_in = Wt;
    const bf16* Wt_1  = Wt + 128 * 128;
    const bf16* Wt_ak = Wt + 128 * 128 + 1024 * 128;

    float* out_logits = (float*)d_out;
    float* out_value  = (float*)d_out + N;

    // CSR (graph shared by all 3 GAT layers) + weight prep
    zero_kernel<<<(2 * N + 255) / 256, 256, 0, stream>>>(cntcur, 2 * N);
    count_kernel<<<(ET + 255) / 256, 256, 0, stream>>>(ei, cnt, E, N);
    transpose_w_kernel<<<dim3(16, 4, 7), 256, 0, stream>>>(
        W_in, c1_Wl, c1_Wr, a_Wl, a_Wr, k_Wl, k_Wr, Wt);
    bias_kernel<<<12, 256, 0, stream>>>(c1_bl, c1_br, a_bl, a_br, k_bl, k_br, b1cat, bakcat);
    scan_kernel<<<1, 1024, 0, stream>>>(cnt, rowptr, N);
    scatter_kernel<<<(ET + 255) / 256, 256, 0, stream>>>(ei, rowptr, cursor, csr_off, E, N);

    // h0 = relu(x @ W_in + b_in)
    gemm_mfma_kernel<<<dim3(MB, 1), 256, 0, stream>>>(x, Wt_in, b_in, h0, nullptr, N, 128, 1);
    // layer-1: [xl1|xr1] = h0 @ [Wl|Wr]  (bf16, cols 0..1023, row stride 2048)
    gemm_mfma_kernel<<<dim3(MB, 8), 256, 0, stream>>>(h0, Wt_1, b1cat, nullptr, cat, Npad, 2048, 0);
    gat_kernel<<<N, 256, 0, stream>>>(cat, cat + 512, c1_att, rowptr, csr_off,
                                      h0, c1_b, ln1_g, ln1_b, h1,
                                      nullptr, nullptr, nullptr, 0);
    // actor+critic: [xla|xra|xlk|xrk] = h1 @ [aWl|aWr|kWl|kWr]
    gemm_mfma_kernel<<<dim3(MB, 16), 256, 0, stream>>>(h1, Wt_ak, bakcat, nullptr, cat, Npad, 2048, 0);
    gat_kernel<<<N, 256, 0, stream>>>(cat, cat + 512, a_att, rowptr, csr_off,
                                      h1, a_b, aln_g, aln_b, nullptr,
                                      ah_W, ah_b, out_logits, 1);
    gat_kernel<<<N, 256, 0, stream>>>(cat + 1024, cat + 1536, k_att, rowptr, csr_off,
                                      h1, k_b, kln_g, kln_b, nullptr,
                                      kh_W, kh_b, out_value, 1);
}